// Round 5
// baseline (14.374 us; speedup 1.0000x reference)
//
#include <hip/hip_runtime.h>
#include <math.h>

// Problem shape (fixed by the reference setup_inputs): B=4, D=32, H=32, W=16
#define NB 4
#define ND 32
#define NH 32
#define NW 16
#define CPS (ND * NH)            // 1024 (d,h)-columns per sample
#define VPS (CPS * NW)           // 16384 voxels per sample
#define NBLK 128                 // 4 samples x 4 pred-chunks x 8 target-chunks
#define PCOLS 256                // pred columns per block
#define TCOLS 128                // target columns per block

// Single fused kernel.
//   Phase A: thread t computes min/max occupied w of its own pred column
//            (pred = logit > 0 <=> sigmoid > 0.5) from 4 float4 loads via a
//            16-bit occupancy mask + ffs/clz; threads 0..127 do the same for
//            the block's target columns (t > 0.5) into LDS.
//   Phase B: max over occupied (pw,tw) within a column pair = max over the 4
//            extreme-w combos (convexity in each variable). Thread owns one
//            pred column x 128 target columns; __mul24 (full-rate) squares.
//   Phase C: block max -> private agent-scope (sc1) slot, then one ticket
//            atomicAdd. Winner = ((old+1) & 127)==0 — true exactly once per
//            128 increments for ANY initial counter value, so the ticket
//            survives the 0xAA ws-poison and graph replays with NO init and
//            NO threadfence/L2-writeback (R2's 68us lesson: all cross-block
//            data flows through coherent-point atomics only).
__global__ __launch_bounds__(256) void hd_one(
    const float* __restrict__ logits, const float* __restrict__ targets,
    int* bmax, unsigned* cnt, float* __restrict__ out) {
    __shared__ int2 s_te[TCOLS];
    __shared__ int s_red[4];
    __shared__ int s_win;

    int bid = blockIdx.x;                 // s*32 + pchunk*8 + tchunk
    int s = bid >> 5;
    int pchunk = (bid >> 3) & 3;
    int tchunk = bid & 7;
    int tid = threadIdx.x;                // 0..255

    // ---- Phase A: column extremes ----
    int pcol = pchunk * PCOLS + tid;
    const float4* pp = (const float4*)(logits + s * VPS + pcol * NW);
    unsigned pmsk = 0;
#pragma unroll
    for (int j = 0; j < 4; ++j) {
        float4 v = pp[j];
        pmsk |= (v.x > 0.0f ? 1u : 0u) << (4 * j);
        pmsk |= (v.y > 0.0f ? 1u : 0u) << (4 * j + 1);
        pmsk |= (v.z > 0.0f ? 1u : 0u) << (4 * j + 2);
        pmsk |= (v.w > 0.0f ? 1u : 0u) << (4 * j + 3);
    }
    int pe_min = pmsk ? (__ffs(pmsk) - 1) : 1000;
    int pe_max = pmsk ? (31 - __clz(pmsk)) : -1;

    if (tid < TCOLS) {
        int tcol = tchunk * TCOLS + tid;
        const float4* tp = (const float4*)(targets + s * VPS + tcol * NW);
        unsigned tmsk = 0;
#pragma unroll
        for (int j = 0; j < 4; ++j) {
            float4 v = tp[j];
            tmsk |= (v.x > 0.5f ? 1u : 0u) << (4 * j);
            tmsk |= (v.y > 0.5f ? 1u : 0u) << (4 * j + 1);
            tmsk |= (v.z > 0.5f ? 1u : 0u) << (4 * j + 2);
            tmsk |= (v.w > 0.5f ? 1u : 0u) << (4 * j + 3);
        }
        s_te[tid] = make_int2(tmsk ? (__ffs(tmsk) - 1) : 1000,
                              tmsk ? (31 - __clz(tmsk)) : -1);
    }
    __syncthreads();

    // ---- Phase B: pair max (same-address LDS reads broadcast: conflict-free) ----
    int pd = pcol >> 5, ph = pcol & 31;
    int td0 = (tchunk * TCOLS) >> 5;
    int best = -1;
#pragma unroll 8
    for (int i = 0; i < TCOLS; ++i) {
        int2 te = s_te[i];
        int dd = pd - (td0 + (i >> 5));
        int dh = ph - (i & 31);
        int b2 = __mul24(dd, dd) + __mul24(dh, dh);
        int a = pe_min - te.x, c = pe_min - te.y;
        int d = pe_max - te.x, e = pe_max - te.y;
        int q = max(max(__mul24(a, a), __mul24(c, c)),
                    max(__mul24(d, d), __mul24(e, e)));
        int cand = b2 + q;
        best = (te.y >= 0) ? max(best, cand) : best;   // skip empty target col
    }
    if (pe_max < 0) best = -1;            // empty pred column: discard

    // block reduce
#pragma unroll
    for (int m = 32; m >= 1; m >>= 1) best = max(best, __shfl_xor(best, m, 64));
    if ((tid & 63) == 0) s_red[tid >> 6] = best;
    __syncthreads();

    // ---- Phase C: coherent-point handshake ----
    if (tid == 0) {
        int mx = max(max(s_red[0], s_red[1]), max(s_red[2], s_red[3]));
        __hip_atomic_store(&bmax[bid], mx, __ATOMIC_RELAXED,
                           __HIP_MEMORY_SCOPE_AGENT);
        // store must be complete at the coherent point before the ticket lands
        asm volatile("s_waitcnt vmcnt(0)" ::: "memory");
        unsigned old = atomicAdd(cnt, 1u);            // device scope by default
        s_win = (((old + 1u) & (NBLK - 1u)) == 0u);
    }
    __syncthreads();

    if (s_win && tid < 64) {
        // lanes grouped 16 per sample; sample g owns bmax[32g .. 32g+32)
        int g = tid >> 4, j = tid & 15;
        int m1 = __hip_atomic_load(&bmax[g * 32 + j], __ATOMIC_RELAXED,
                                   __HIP_MEMORY_SCOPE_AGENT);
        int m2 = __hip_atomic_load(&bmax[g * 32 + 16 + j], __ATOMIC_RELAXED,
                                   __HIP_MEMORY_SCOPE_AGENT);
        int m = max(m1, m2);
#pragma unroll
        for (int k = 8; k >= 1; k >>= 1) m = max(m, __shfl_xor(m, k, 64));
        float hd = (m < 0) ? INFINITY : sqrtf((float)m);
        float ssum = hd + __shfl_xor(hd, 16, 64);     // pair of sample groups
        ssum += __shfl_xor(ssum, 32, 64);             // all four samples
        if (tid == 0) out[0] = ssum * (1.0f / NB);
    }
}

extern "C" void kernel_launch(void* const* d_in, const int* in_sizes, int n_in,
                              void* d_out, int out_size, void* d_ws, size_t ws_size,
                              hipStream_t stream) {
    const float* logits  = (const float*)d_in[0];
    const float* targets = (const float*)d_in[1];
    float* out = (float*)d_out;

    int* bmax = (int*)d_ws;                   // NBLK slots, rewritten every call
    unsigned* cnt = (unsigned*)((char*)d_ws + NBLK * sizeof(int));  // no init needed

    hd_one<<<NBLK, 256, 0, stream>>>(logits, targets, bmax, cnt, out);
}

// Round 6
// 12.431 us; speedup vs baseline: 1.1563x; 1.1563x over previous
//
#include <hip/hip_runtime.h>
#include <math.h>

// Problem shape (fixed by the reference setup_inputs): B=4, D=32, H=32, W=16
#define NB 4
#define ND 32
#define NH 32
#define NW 16
#define CPS (ND * NH)            // 1024 (d,h)-columns per sample
#define VPS (CPS * NW)           // 16384 voxels per sample
#define NBLK 256                 // 4 samples x 8 pred-chunks x 8 target-chunks
#define PC 128                   // pred columns per block
#define TC 128                   // target columns per block

// Single-dispatch fused kernel, full chip (256 blocks x 512 threads).
//
// Phase A (threads 0..255): one thread per column: 4 float4 loads -> 16-bit
//   occupancy mask (pred: logit > 0 <=> sigmoid > 0.5; target: t > 0.5),
//   extremes via ffs/clz -> int2 in LDS.
// Phase B (all 512): thread owns pred col (tid>>2) x 32 target cols
//   (tg + 4i, tg = tid&3 -> 4-address LDS broadcast, conflict-free).
//   Strength reduction: tl = tg+4i => td = i>>3, th = 4(i&7)+tg, so the
//   (d,h) parts become 4+8 precomputed squares indexed by compile-time
//   constants after full unroll. w-part: max over the 4 extreme combos
//   = q^2 with q = max(pmax - tmin, tmax - pmin) (max |interval diff|).
//   ~9 ops/pair, 32 iters -> body ~0.5us at 8 waves/CU (R5's mistake:
//   1 wave/SIMD on half the chip left LDS latency exposed).
// Phase C: agent-scope (sc1) store to a private slot + vmcnt(0) + one
//   device-scope ticket atomicAdd. Winner = ((old+1) & 255)==0 — exactly
//   once per 256 increments for ANY start value, so no init, poison- and
//   replay-proof (proven R5). Winner wave reads all 256 slots (4/lane,
//   agent-scope), reduces, writes mean.
__global__ __launch_bounds__(512) void hd_one(
    const float* __restrict__ logits, const float* __restrict__ targets,
    int* bmax, unsigned* cnt, float* __restrict__ out) {
    __shared__ int2 s_pe[PC];
    __shared__ int2 s_te[TC];
    __shared__ int s_red[8];
    __shared__ int s_win;

    int bid = blockIdx.x;                 // s*64 + pchunk*8 + tchunk
    int s = bid >> 6;
    int pchunk = (bid >> 3) & 7;
    int tchunk = bid & 7;
    int tid = threadIdx.x;                // 0..511

    // ---- Phase A: column extremes (threads 0..255) ----
    if (tid < 256) {
        bool isp = tid < PC;
        int lc = tid & (PC - 1);
        int col = (isp ? pchunk : tchunk) * PC + lc;
        const float4* p4 =
            (const float4*)((isp ? logits : targets) + s * VPS + col * NW);
        float thr = isp ? 0.0f : 0.5f;
        unsigned msk = 0;
#pragma unroll
        for (int j = 0; j < 4; ++j) {
            float4 v = p4[j];
            msk |= (v.x > thr ? 1u : 0u) << (4 * j);
            msk |= (v.y > thr ? 1u : 0u) << (4 * j + 1);
            msk |= (v.z > thr ? 1u : 0u) << (4 * j + 2);
            msk |= (v.w > thr ? 1u : 0u) << (4 * j + 3);
        }
        int2 e = make_int2(msk ? (__ffs(msk) - 1) : 1000,
                           msk ? (31 - __clz(msk)) : -1);
        if (isp) s_pe[lc] = e; else s_te[lc] = e;
    }
    __syncthreads();

    // ---- Phase B: pair max ----
    int lp = tid >> 2;                    // local pred column 0..127
    int tg = tid & 3;
    int2 pe = s_pe[lp];
    int pcol = pchunk * PC + lp;
    int pd = pcol >> 5, ph = pcol & 31;

    int dd2[4], dh2[8];
#pragma unroll
    for (int k = 0; k < 4; ++k) { int d = pd - (tchunk * 4 + k); dd2[k] = d * d; }
#pragma unroll
    for (int j = 0; j < 8; ++j) { int h = ph - (4 * j + tg); dh2[j] = h * h; }

    int best = -1;
#pragma unroll
    for (int i = 0; i < 32; ++i) {
        int2 te = s_te[tg + 4 * i];
        int q = max(pe.y - te.x, te.y - pe.x);
        int cand = dd2[i >> 3] + dh2[i & 7] + q * q;
        best = (te.y >= 0) ? max(best, cand) : best;   // skip empty target col
    }
    if (pe.y < 0) best = -1;              // empty pred column: discard

    // block reduce (8 waves)
#pragma unroll
    for (int m = 32; m >= 1; m >>= 1) best = max(best, __shfl_xor(best, m, 64));
    if ((tid & 63) == 0) s_red[tid >> 6] = best;
    __syncthreads();

    // ---- Phase C: coherent-point handshake ----
    if (tid == 0) {
        int mx = s_red[0];
#pragma unroll
        for (int i = 1; i < 8; ++i) mx = max(mx, s_red[i]);
        __hip_atomic_store(&bmax[bid], mx, __ATOMIC_RELAXED,
                           __HIP_MEMORY_SCOPE_AGENT);
        // store must reach the coherent point before the ticket lands
        asm volatile("s_waitcnt vmcnt(0)" ::: "memory");
        unsigned old = atomicAdd(cnt, 1u);            // device scope by default
        s_win = (((old + 1u) & (NBLK - 1u)) == 0u) ? 1 : 0;
    }
    __syncthreads();

    if (s_win && tid < 64) {
        // lane l holds bids 4l..4l+3; sample = l>>4 (64 bids per sample)
        int b0 = tid * 4;
        int m0 = __hip_atomic_load(&bmax[b0 + 0], __ATOMIC_RELAXED,
                                   __HIP_MEMORY_SCOPE_AGENT);
        int m1 = __hip_atomic_load(&bmax[b0 + 1], __ATOMIC_RELAXED,
                                   __HIP_MEMORY_SCOPE_AGENT);
        int m2 = __hip_atomic_load(&bmax[b0 + 2], __ATOMIC_RELAXED,
                                   __HIP_MEMORY_SCOPE_AGENT);
        int m3 = __hip_atomic_load(&bmax[b0 + 3], __ATOMIC_RELAXED,
                                   __HIP_MEMORY_SCOPE_AGENT);
        int m = max(max(m0, m1), max(m2, m3));
#pragma unroll
        for (int k = 8; k >= 1; k >>= 1) m = max(m, __shfl_xor(m, k, 64));
        float hd = (m < 0) ? INFINITY : sqrtf((float)m);
        // lanes 0,16,32,48 hold samples 0..3
        float ssum = __shfl(hd, 0, 64) + __shfl(hd, 16, 64) +
                     __shfl(hd, 32, 64) + __shfl(hd, 48, 64);
        if (tid == 0) out[0] = ssum * (1.0f / NB);
    }
}

extern "C" void kernel_launch(void* const* d_in, const int* in_sizes, int n_in,
                              void* d_out, int out_size, void* d_ws, size_t ws_size,
                              hipStream_t stream) {
    const float* logits  = (const float*)d_in[0];
    const float* targets = (const float*)d_in[1];
    float* out = (float*)d_out;

    int* bmax = (int*)d_ws;                   // NBLK slots, rewritten every call
    unsigned* cnt = (unsigned*)((char*)d_ws + NBLK * sizeof(int));  // no init needed

    hd_one<<<NBLK, 512, 0, stream>>>(logits, targets, bmax, cnt, out);
}